// Round 2
// baseline (38.190 us; speedup 1.0000x reference)
//
#include <hip/hip_runtime.h>

// SubpixelReshuffleLayer: out[b, 2i+r2, 2j+r1, g] = x[b, i, j, 4g + 2r1 + r2]
// x: [32,256,256,12] f32, out: [32,512,512,3] f32.
//
// Register-only permute (no LDS, no barrier):
//   thread t owns one input-pixel PAIR (j0=2u, j0+1) of row ri = b*256+i.
//   It loads 24 consecutive floats (6x float4, contiguous across the wave),
//   permutes in registers with compile-time indices, and writes one
//   12-float chunk (3x float4) into each of the two output rows 2*ri+r2:
//     row r2 chunk = { v[r2], v[4+r2], v[8+r2], v[2+r2], v[6+r2], v[10+r2],
//                      v[12+r2], v[16+r2], v[20+r2], v[14+r2], v[18+r2], v[22+r2] }
//   Output flat row index = 2*ri + r2 (since b*512 + 2i + r2 = 2*(b*256+i)+r2).

#define THREADS 256

__global__ __launch_bounds__(THREADS)
void subpixel_reshuffle_kernel(const float4* __restrict__ in,
                               float4* __restrict__ out) {
    const int gid = blockIdx.x * THREADS + threadIdx.x;
    const int u  = gid & 127;   // pixel-pair index within the input row (0..127)
    const int ri = gid >> 7;    // flat input row b*256+i (0..8191)

    // Load 24 consecutive floats = input pixels (2u) and (2u+1), all 12 ch.
    const float4* ip = in + ri * 768 + 6 * u;   // 768 float4 per input row
    float v[24];
    *reinterpret_cast<float4*>(&v[0])  = ip[0];
    *reinterpret_cast<float4*>(&v[4])  = ip[1];
    *reinterpret_cast<float4*>(&v[8])  = ip[2];
    *reinterpret_cast<float4*>(&v[12]) = ip[3];
    *reinterpret_cast<float4*>(&v[16]) = ip[4];
    *reinterpret_cast<float4*>(&v[20]) = ip[5];

    // Two output rows, 12 floats each; all indices compile-time constant.
    #pragma unroll
    for (int r2 = 0; r2 < 2; ++r2) {
        float o[12];
        o[0]  = v[r2];      o[1]  = v[4 + r2];  o[2]  = v[8 + r2];
        o[3]  = v[2 + r2];  o[4]  = v[6 + r2];  o[5]  = v[10 + r2];
        o[6]  = v[12 + r2]; o[7]  = v[16 + r2]; o[8]  = v[20 + r2];
        o[9]  = v[14 + r2]; o[10] = v[18 + r2]; o[11] = v[22 + r2];

        float4* op = out + (2 * ri + r2) * 384 + 3 * u;  // 384 float4 per out row
        op[0] = *reinterpret_cast<const float4*>(&o[0]);
        op[1] = *reinterpret_cast<const float4*>(&o[4]);
        op[2] = *reinterpret_cast<const float4*>(&o[8]);
    }
}

extern "C" void kernel_launch(void* const* d_in, const int* in_sizes, int n_in,
                              void* d_out, int out_size, void* d_ws, size_t ws_size,
                              hipStream_t stream) {
    const float* x = (const float*)d_in[0];
    float* y = (float*)d_out;
    // total pixel-pairs = B*H*(W/2) = 32*256*128 = 1,048,576
    const int n_threads_total = in_sizes[0] / 24;
    const int n_blocks = n_threads_total / THREADS;   // 4096
    subpixel_reshuffle_kernel<<<n_blocks, THREADS, 0, stream>>>(
        (const float4*)x, (float4*)y);
}

// Round 4
// 34.171 us; speedup vs baseline: 1.1176x; 1.1176x over previous
//
#include <hip/hip_runtime.h>

// SubpixelReshuffleLayer: out[b, 2i+r2, 2j+r1, g] = x[b, i, j, 4g + 2r1 + r2]
// x: [32,256,256,12] f32, out: [32,512,512,3] f32.
//
// Wave-private LDS permute, barrier-free:
//   Each wave owns 128 input pixels (half an input row; 1536 floats = 6 KB).
//   Input pixels [j0, j0+128) of row ri map to contiguous output runs
//   [ (2ri+r2)*1536 + 6*j0, +768 ) for r2 in {0,1}.
//   phase 1: 6x coalesced global float4 loads -> scattered LDS writes
//            (wave-private slice; same-wave DS ops are in-order, no barrier)
//   phase 2: contiguous ds_read_b128 -> coalesced NONTEMPORAL float4 stores
//            (nt keeps the 100 MB output stream from evicting the
//             LLC-resident input)

#define THREADS 256
#define WAVE_FLOATS 1536   // 128 pixels * 12 ch
#define WAVE_VEC4   (WAVE_FLOATS / 4)   // 384

typedef float nf4 __attribute__((ext_vector_type(4)));  // native vec for builtins

__global__ __launch_bounds__(THREADS)
void subpixel_reshuffle_kernel(const float4* __restrict__ in,
                               float* __restrict__ out) {
    __shared__ float lds[4 * WAVE_FLOATS];   // 24 KB, one 6 KB slice per wave

    const int wave = threadIdx.x >> 6;
    const int lane = threadIdx.x & 63;
    float* wlds = &lds[wave * WAVE_FLOATS];

    const int gw   = blockIdx.x * 4 + wave;  // global wave id, 0..16383
    const int ri   = gw >> 1;                // flat input row b*256+i
    const int half = gw & 1;                 // which half-row (j0 = 128*half)

    // Phase 1: coalesced loads, scattered wave-private LDS writes.
    // f4 q holds channels [4g,4g+3] of local pixel p (q = 3p+g):
    //   .x -> (r1=0,r2=0), .y -> (r1=0,r2=1), .z -> (r1=1,r2=0), .w -> (r1=1,r2=1)
    // LDS pos = r2*768 + 6p + 3r1 + g
    const float4* ip = in + (long long)gw * WAVE_VEC4;
    #pragma unroll
    for (int k = 0; k < 6; ++k) {
        const int q = k * 64 + lane;        // 0..383
        const float4 v = ip[q];
        const int p = q / 3;                // local pixel 0..127
        const int g = q - 3 * p;            // channel group 0..2
        const int base = 6 * p + g;
        wlds[base]       = v.x;   // r1=0, r2=0
        wlds[base + 3]   = v.z;   // r1=1, r2=0
        wlds[base + 768] = v.y;   // r1=0, r2=1
        wlds[base + 771] = v.w;   // r1=1, r2=1
    }

    // Same-wave LDS RAW: DS ops from one wave are processed in order; add an
    // explicit lgkmcnt(0) + compiler memory fence for safety (no s_barrier).
    asm volatile("" ::: "memory");
    __builtin_amdgcn_s_waitcnt(0xc07f);   // lgkmcnt(0), vmcnt/expcnt unchanged
    asm volatile("" ::: "memory");

    // Phase 2: contiguous LDS reads, coalesced nontemporal stores.
    #pragma unroll
    for (int r2 = 0; r2 < 2; ++r2) {
        float* op = out + (2 * ri + r2) * 1536 + 768 * half;
        const float* src = wlds + r2 * 768;
        #pragma unroll
        for (int k = 0; k < 3; ++k) {
            const int q = k * 64 + lane;    // 0..191
            const nf4 v = *reinterpret_cast<const nf4*>(&src[4 * q]);
            __builtin_nontemporal_store(v, reinterpret_cast<nf4*>(&op[4 * q]));
        }
    }
}

extern "C" void kernel_launch(void* const* d_in, const int* in_sizes, int n_in,
                              void* d_out, int out_size, void* d_ws, size_t ws_size,
                              hipStream_t stream) {
    const float* x = (const float*)d_in[0];
    float* y = (float*)d_out;
    const int n_waves  = in_sizes[0] / WAVE_FLOATS;  // 16384
    const int n_blocks = n_waves / 4;                // 4096
    subpixel_reshuffle_kernel<<<n_blocks, THREADS, 0, stream>>>(
        (const float4*)x, y);
}